// Round 1
// baseline (79.893 us; speedup 1.0000x reference)
//
#include <hip/hip_runtime.h>
#include <hip/hip_bf16.h>
#include <cstdint>
#include <cstddef>

typedef _Float16 f16x8 __attribute__((ext_vector_type(8)));
typedef _Float16 f16x4 __attribute__((ext_vector_type(4)));
typedef float    f32x4 __attribute__((ext_vector_type(4)));

#define MFMA16(a,b,c) __builtin_amdgcn_mfma_f32_16x16x32_f16((a),(b),(c),0,0,0)

// Workspace layout (in _Float16 elements):
//   W1T  [15][64][256] at 0        (245760)
//   W16T [64][384]     at 245760   (24576)   k-index sp: x col = 1816+sp, zero for sp<4 or sp>=360
//   W2T  [4][64][256]  at 270336   (65536)
//   W3T  [272][256]    at 335872   (69632)   rows >= 260 are zero
// total 405504 halfs = 811008 bytes

__global__ void tea_prep(const float* __restrict__ W1, const float* __restrict__ W16,
                         const float* __restrict__ W2, const float* __restrict__ W3,
                         _Float16* __restrict__ ws)
{
    int i = blockIdx.x * blockDim.x + threadIdx.x;
    if (i < 245760) {
        int k = i >> 14, r = i & 16383, o = r >> 8, s = r & 255;
        ws[i] = (_Float16)W1[((k << 8) | s) * 64 + o];
    } else if (i < 270336) {
        int r = i - 245760, o = r / 384, sp = r - o * 384;
        float v = (sp >= 4 && sp < 360) ? W16[(sp - 4) * 64 + o] : 0.f;
        ws[i] = (_Float16)v;
    } else if (i < 335872) {
        int r = i - 270336, g = r >> 14, rr = r & 16383, o = rr >> 8, s = rr & 255;
        ws[i] = (_Float16)W2[((g << 8) | s) * 64 + o];
    } else if (i < 405504) {
        int r = i - 335872, o = r >> 8, s = r & 255;
        ws[i] = (_Float16)((o < 260) ? W3[s * 260 + o] : 0.f);
    }
}

// 64x64-output GEMM pass over K = nkk*32.  4 waves, each a 32x32 quadrant as 2x2
// 16x16 tiles.  A and B fragments use the SAME (lanegroup,elem)->k map (kk*32+8*lg+j),
// so any HW K-permutation cancels.  C/D layout: col=lane&15, row=4*(lane>>4)+reg.
// ACH: A from the 3-slot x-chunk ring (xbase = global x column base).
// !ACH: A from a [64][264] LDS matrix.  BG: B from global (stride bstride), else
// from the [64][264] staged weight tile.
template<bool ACH, bool BG>
__device__ __forceinline__ void gemm_pass(
    int lg, int lr, int r0, int c0,
    const _Float16* __restrict__ xch, int xbase,
    const _Float16* __restrict__ amat,
    const _Float16* __restrict__ wt,
    const _Float16* __restrict__ bglob, int bstride,
    int nkk, const float* __restrict__ bias,
    _Float16* __restrict__ dst, int dbase)
{
    f32x4 a00 = {0.f,0.f,0.f,0.f}, a01 = {0.f,0.f,0.f,0.f};
    f32x4 a10 = {0.f,0.f,0.f,0.f}, a11 = {0.f,0.f,0.f,0.f};
    for (int kk = 0; kk < nkk; ++kk) {
        int kloc = kk * 32 + lg * 8;
        f16x8 A0, A1, B0, B1;
        if (ACH) {
            int cg = xbase + kloc;
            int slot = (cg >> 7) % 3;
            int off  = cg & 127;
            const _Float16* p = xch + (slot * 64 + r0 + lr) * 136 + off;
            A0 = *(const f16x8*)p;
            A1 = *(const f16x8*)(p + 16 * 136);
        } else {
            const _Float16* p = amat + (r0 + lr) * 264 + kloc;
            A0 = *(const f16x8*)p;
            A1 = *(const f16x8*)(p + 16 * 264);
        }
        if (BG) {
            const _Float16* q = bglob + (size_t)(c0 + lr) * bstride + kloc;
            B0 = *(const f16x8*)q;
            B1 = *(const f16x8*)(q + 16 * bstride);
        } else {
            const _Float16* q = wt + (c0 + lr) * 264 + kloc;
            B0 = *(const f16x8*)q;
            B1 = *(const f16x8*)(q + 16 * 264);
        }
        a00 = MFMA16(A0, B0, a00);
        a01 = MFMA16(A0, B1, a01);
        a10 = MFMA16(A1, B0, a10);
        a11 = MFMA16(A1, B1, a11);
    }
    float bv0 = bias[c0 + lr];
    float bv1 = bias[c0 + 16 + lr];
    #pragma unroll
    for (int j = 0; j < 4; ++j) {
        int rA = r0 + lg * 4 + j;
        int rB = rA + 16;
        float v;
        v = a00[j] + bv0; v = v > 0.f ? v : 0.f; dst[rA * 264 + dbase + c0 + lr]      = (_Float16)v;
        v = a01[j] + bv1; v = v > 0.f ? v : 0.f; dst[rA * 264 + dbase + c0 + 16 + lr] = (_Float16)v;
        v = a10[j] + bv0; v = v > 0.f ? v : 0.f; dst[rB * 264 + dbase + c0 + lr]      = (_Float16)v;
        v = a11[j] + bv1; v = v > 0.f ? v : 0.f; dst[rB * 264 + dbase + c0 + 16 + lr] = (_Float16)v;
    }
}

// LDS (153600 B total, < 160 KiB):
//   xch [3][64][136] f16 at 0       (52224 B)   3-slot ring of 128-col x chunks
//   wt  [64][264]    f16 at 52224   (33792 B)   staged W1T[k] / W2T[g]
//   ysm [64][264]    f16 at 86016   (33792 B)   per-group y (4 windows * 64 cols)
//   zsm [64][264]    f16 at 119808  (33792 B)   z (layer2 out, 256 cols)
//   phase B: hsm [64][280] f32 at 0 (71680 B)   layer3 h, aliases xch+wt
__global__ __launch_bounds__(256, 1)
void tea_main(const float* __restrict__ x,
              const float* __restrict__ b1,
              const float* __restrict__ b16,
              const float* __restrict__ b2,
              const float* __restrict__ b3,
              const _Float16* __restrict__ ws,
              float* __restrict__ out)
{
    __shared__ _Float16 lds[76800];
    _Float16* xch = lds;                 // [3][64][136]
    _Float16* wt  = lds + 26112;         // [64][264]
    _Float16* ysm = lds + 43008;         // [64][264]
    _Float16* zsm = lds + 59904;         // [64][264]
    float*    hsm = (float*)lds;         // [64][280] (phase B only)

    const int tid = threadIdx.x;
    const int bid = blockIdx.x;
    const int w  = tid >> 6;
    const int l  = tid & 63;
    const int lg = l >> 4;
    const int lr = l & 15;
    const int r0 = (w & 1) * 32;
    const int c0 = (w >> 1) * 32;

    const _Float16* wsW1  = ws;
    const _Float16* wsW16 = ws + 245760;
    const _Float16* wsW2  = ws + 270336;
    const _Float16* wsW3  = ws + 335872;

    const float* xrow = x + (size_t)bid * 64 * 2176;

    float4 creg[8];

    auto issue_chunk = [&](int c) {
        const float* base = xrow + c * 128;
        #pragma unroll
        for (int i = 0; i < 8; ++i) {
            int e = i * 1024 + tid * 4;
            int row = e >> 7, col = e & 127;
            creg[i] = *(const float4*)(base + (size_t)row * 2176 + col);
        }
    };
    auto write_chunk = [&](int c) {
        int slot = c % 3;
        #pragma unroll
        for (int i = 0; i < 8; ++i) {
            int e = i * 1024 + tid * 4;
            int row = e >> 7, col = e & 127;
            f16x4 h;
            h[0] = (_Float16)creg[i].x; h[1] = (_Float16)creg[i].y;
            h[2] = (_Float16)creg[i].z; h[3] = (_Float16)creg[i].w;
            *(f16x4*)(xch + (slot * 64 + row) * 136 + col) = h;
        }
    };
    auto stage_wt = [&](const _Float16* src) {
        #pragma unroll
        for (int i = 0; i < 8; ++i) {
            int e = i * 2048 + tid * 8;
            int row = e >> 8, col = e & 255;
            f16x8 v = *(const f16x8*)(src + e);
            *(f16x8*)(wt + row * 264 + col) = v;
        }
    };

    // prologue: chunk 0 staged, chunk 1 in flight
    issue_chunk(0);
    write_chunk(0);
    issue_chunk(1);

    for (int g = 0; g < 4; ++g) {
        #pragma unroll 1
        for (int j = 0; j < 4; ++j) {
            int k = g * 4 + j;                 // k==15 -> y16 pseudo-window
            __syncthreads();                   // prior pass compute done; chunk k+1 loads drained
            write_chunk(k + 1);                // chunk k+1 -> slot (k+1)%3
            if (k < 15) stage_wt(wsW1 + k * 16384);
            __syncthreads();
            if (k + 2 <= 16) issue_chunk(k + 2);   // in flight across this pass's compute
            if (k < 15) {
                gemm_pass<true, false>(lg, lr, r0, c0, xch, 128 * k, nullptr, wt,
                                       nullptr, 0, 8, b1 + k * 64, ysm, (k & 3) * 64);
            } else {
                // y16: x cols 1816+sp (chunks 14,15,16 all live in the ring)
                gemm_pass<true, true>(lg, lr, r0, c0, xch, 1816, nullptr, nullptr,
                                      wsW16, 384, 12, b16, ysm, 192);
            }
        }
        // layer 2, group g
        __syncthreads();
        stage_wt(wsW2 + g * 16384);
        __syncthreads();
        gemm_pass<false, false>(lg, lr, r0, c0, nullptr, 0, ysm, wt,
                                nullptr, 0, 8, b2 + g * 64, zsm, g * 64);
    }

    // layer 3: each wave one 16-row strip, 17 col-tiles, B straight from L2
    __syncthreads();
    {
        f16x8 az[8];
        #pragma unroll
        for (int kk = 0; kk < 8; ++kk)
            az[kk] = *(const f16x8*)(zsm + (w * 16 + lr) * 264 + kk * 32 + lg * 8);
        #pragma unroll 1
        for (int t = 0; t < 17; ++t) {
            f32x4 acc = {0.f,0.f,0.f,0.f};
            #pragma unroll
            for (int kk = 0; kk < 8; ++kk) {
                f16x8 B = *(const f16x8*)(wsW3 + (size_t)(t * 16 + lr) * 256 + kk * 32 + lg * 8);
                acc = MFMA16(az[kk], B, acc);
            }
            int o = t * 16 + lr;
            float bv = (o < 260) ? b3[o] : 0.f;
            #pragma unroll
            for (int jj = 0; jj < 4; ++jj) {
                float v = acc[jj] + bv; v = v > 0.f ? v : 0.f;
                hsm[(w * 16 + lg * 4 + jj) * 280 + o] = v;
            }
        }
    }
    __syncthreads();

    // pooling (10 classes x 26) + softmax; lanes 0..15 of each wave handle its 16 rows
    if (l < 16) {
        int row = w * 16 + l;
        float p[10];
        #pragma unroll
        for (int c = 0; c < 10; ++c) {
            float s = 0.f;
            #pragma unroll
            for (int u = 0; u < 26; ++u) s += hsm[row * 280 + c * 26 + u];
            p[c] = s;
        }
        float m = p[0];
        #pragma unroll
        for (int c = 1; c < 10; ++c) m = fmaxf(m, p[c]);
        float e[10], se = 0.f;
        #pragma unroll
        for (int c = 0; c < 10; ++c) { e[c] = expf(p[c] - m); se += e[c]; }
        float inv = 1.f / se;
        float* orow = out + (size_t)(bid * 64 + row) * 10;
        #pragma unroll
        for (int c = 0; c < 10; ++c) orow[c] = e[c] * inv;
    }
}

extern "C" void kernel_launch(void* const* d_in, const int* in_sizes, int n_in,
                              void* d_out, int out_size, void* d_ws, size_t ws_size,
                              hipStream_t stream)
{
    const float* x   = (const float*)d_in[0];
    const float* W1  = (const float*)d_in[1];
    const float* b1  = (const float*)d_in[2];
    const float* W16 = (const float*)d_in[3];
    const float* b16 = (const float*)d_in[4];
    const float* W2  = (const float*)d_in[5];
    const float* b2  = (const float*)d_in[6];
    const float* W3  = (const float*)d_in[7];
    const float* b3  = (const float*)d_in[8];
    float*    out = (float*)d_out;
    _Float16* ws  = (_Float16*)d_ws;

    tea_prep<<<1584, 256, 0, stream>>>(W1, W16, W2, W3, ws);
    tea_main<<<256, 256, 0, stream>>>(x, b1, b16, b2, b3, ws, out);
}